// Round 7
// baseline (91.384 us; speedup 1.0000x reference)
//
#include <hip/hip_runtime.h>
#include <math.h>

#define T_SEQ 2048
#define NH    16
#define NKV   4
// ws layout: tb (sin/cos table, 512KB) @0 ; Kr f16 @1MB (2MB) ; Vt f16 @3MB (2MB) ;
//            Wt f16 @5MB (2MB) ; AO f16 @7MB (8MB). Total 15MB.

typedef __attribute__((ext_vector_type(8)))  _Float16 f16x8;
typedef __attribute__((ext_vector_type(4)))  _Float16 f16x4;
typedef __attribute__((ext_vector_type(2)))  __fp16   fp16x2b;  // cvt_pkrtz result type
typedef __attribute__((ext_vector_type(4)))  float    f32x4;
typedef __attribute__((ext_vector_type(16))) float    f32x16;

#if __has_builtin(__builtin_amdgcn_exp2f)
#define EXP2F(x) __builtin_amdgcn_exp2f(x)
#else
#define EXP2F(x) exp2f(x)
#endif

// 0.125 (1/sqrt(64)) * log2(e): QK^T scores land directly in log2 domain.
#define QSCALE 0.18033688011112042f

// ---------------- fused prep: table | rope_k | V-transpose | W-transpose ------
__global__ __launch_bounds__(256) void prep_kernel(const float* __restrict__ k,
                                                   const float* __restrict__ v,
                                                   const float* __restrict__ w,
                                                   float2* __restrict__ tb,
                                                   _Float16* __restrict__ Kr,
                                                   _Float16* __restrict__ Vt,
                                                   _Float16* __restrict__ Wt)
{
    __shared__ _Float16 L[64 * 72];
    const int bx = blockIdx.x;
    if (bx < 256) {
        // sin/cos table: tb[t*32+i] = {cos, sin}(t * 10000^(-i/32))
        int idx = bx * 256 + threadIdx.x;
        int i = idx & 31, t = idx >> 5;
        float inv = __expf((float)i * (-9.210340371976184f / 32.0f));
        float ang = (float)t * inv;
        tb[idx] = make_float2(cosf(ang), sinf(ang));
    } else if (bx < 2304) {
        // K RoPE (inline trig; independent of tb)
        int idx = (bx - 256) * 256 + threadIdx.x;     // [0, 2*4*2048*32)
        int i   = idx & 31;
        int t   = (idx >> 5) & 2047;
        int bk  = idx >> 16;                          // b*4+kh
        float inv = __expf((float)i * (-9.210340371976184f / 32.0f));
        float ang = (float)t * inv;
        float sn = sinf(ang), cs = cosf(ang);
        const float* src = k + ((size_t)(bk >> 2) * T_SEQ + t) * 256 + (bk & 3) * 64 + i;
        float x1 = src[0], x2 = src[32];
        _Float16* dst = Kr + ((size_t)bk * T_SEQ + t) * 64 + i;
        dst[0]  = (_Float16)(x1 * cs - x2 * sn);
        dst[32] = (_Float16)(x2 * cs + x1 * sn);
    } else if (bx < 2560) {
        // V transpose via LDS (both sides coalesced)
        const int id = bx - 2304;                     // 32 t-tiles x 8 bk
        const int t0 = (id & 31) * 64, bk = id >> 5;
        const int b = bk >> 2, kh = bk & 3;
        const int rr = threadIdx.x >> 2, pp = threadIdx.x & 3;
        const float* src = v + ((size_t)(b * T_SEQ + t0 + rr)) * 256 + kh * 64 + pp * 16;
        f32x4 s0 = *(const f32x4*)(src), s1 = *(const f32x4*)(src + 4);
        f32x4 s2 = *(const f32x4*)(src + 8), s3 = *(const f32x4*)(src + 12);
        _Float16* lp = &L[rr * 72 + pp * 16];
        #pragma unroll
        for (int j = 0; j < 4; ++j) { lp[j] = (_Float16)s0[j]; lp[4+j] = (_Float16)s1[j];
                                      lp[8+j] = (_Float16)s2[j]; lp[12+j] = (_Float16)s3[j]; }
        __syncthreads();
        f16x8 w0, w1;
        #pragma unroll
        for (int j = 0; j < 8; ++j) w0[j] = L[(pp * 16 + j) * 72 + rr];
        #pragma unroll
        for (int j = 0; j < 8; ++j) w1[j] = L[(pp * 16 + 8 + j) * 72 + rr];
        _Float16* dst = Vt + ((size_t)bk * 64 + rr) * T_SEQ + t0 + pp * 16;
        *(f16x8*)dst = w0; *(f16x8*)(dst + 8) = w1;
    } else {
        // W transpose via LDS
        const int id = bx - 2560;                     // 16 k-tiles x 16 n-tiles
        const int k0 = (id & 15) * 64, n0 = (id >> 4) * 64;
        const int rr = threadIdx.x >> 2, pp = threadIdx.x & 3;
        const float* src = w + (size_t)(k0 + rr) * 1024 + n0 + pp * 16;
        f32x4 s0 = *(const f32x4*)(src), s1 = *(const f32x4*)(src + 4);
        f32x4 s2 = *(const f32x4*)(src + 8), s3 = *(const f32x4*)(src + 12);
        _Float16* lp = &L[rr * 72 + pp * 16];
        #pragma unroll
        for (int j = 0; j < 4; ++j) { lp[j] = (_Float16)s0[j]; lp[4+j] = (_Float16)s1[j];
                                      lp[8+j] = (_Float16)s2[j]; lp[12+j] = (_Float16)s3[j]; }
        __syncthreads();
        f16x8 w0, w1;
        #pragma unroll
        for (int j = 0; j < 8; ++j) w0[j] = L[(pp * 16 + j) * 72 + rr];
        #pragma unroll
        for (int j = 0; j < 8; ++j) w1[j] = L[(pp * 16 + 8 + j) * 72 + rr];
        _Float16* dst = Wt + (size_t)(n0 + rr) * 1024 + k0 + pp * 16;
        *(f16x8*)dst = w0; *(f16x8*)(dst + 8) = w1;
    }
}

// ---------------- flash attention: 4 waves x 32q bands, 32x32 MFMA ----------
// Balanced mapping: tasks sorted by descending tile count, interleaved so the
// two blocks co-resident on a CU (bid i, i+256 or consecutive) have adjacent
// lengths -> ~2 waves/SIMD for the whole wall. Depth-2 register prefetch: at
// tile t issue loads for t+2, ds_write the (complete) t+1 set -> no vmcnt
// stall. Swapped QK^T (32x32), in-lane softmax stats, log2 domain, T12 repack.

__global__ __launch_bounds__(256) void attn_kernel(const float* __restrict__ q,
                                                   const float2* __restrict__ tb,
                                                   const _Float16* __restrict__ Kr,
                                                   const _Float16* __restrict__ Vt,
                                                   _Float16* __restrict__ AO)
{
    __shared__ _Float16 smem[16384];   // Ks[2]@0/4096, Vs[2]@8192/12288; Os reuse

    const int tid  = threadIdx.x;
    const int wid  = tid >> 6;
    const int lane = tid & 63;
    // ---- balanced interleaved task mapping ----
    const int bid = blockIdx.x;
    const int s   = (bid < 256) ? (2 * bid) : (2 * bid - 511);
    const int bh  = s & 31;                        // b*16+h
    const int c   = 15 - (s >> 5);                 // q-chunk (128 rows)
    const int b = bh >> 4, h = bh & 15;
    const int bkh = b * NKV + (h >> 2);
    const int hi = lane >> 5;                      // half-wave
    const int qc = lane & 31;                      // q within band / A-row index
    const int qlo = c * 128 + wid * 32;            // wave's q band start
    const int tq  = qlo + qc;                      // this lane's stat-q row
    const int NT  = 2 * c + 2;

    // ---- staging geometry (256 threads stage 64x64 K + 64x64 V per tile) ----
    const int srow   = wid * 16 + (lane >> 3);
    const int schunk = lane & 7;
    const _Float16* kgbase = Kr + (size_t)bkh * T_SEQ * 64;
    const _Float16* vgbase = Vt + (size_t)bkh * 64 * T_SEQ;
    const int kd0 = srow * 64 + ((schunk ^ (srow & 7)) * 8);
    const int kd1 = kd0 + 8 * 64;

    // two named staging register sets (ping-pong; rule #20: no dynamic index)
    f16x8 sAK0, sAK1, sAV0, sAV1, sBK0, sBK1, sBV0, sBV1;
    {   // prologue: issue T0 loads first
        const _Float16* kg = kgbase + (size_t)srow * 64 + schunk * 8;
        sAK0 = *(const f16x8*)(kg);
        sAK1 = *(const f16x8*)(kg + 8 * 64);
        const _Float16* vg = vgbase + (size_t)srow * T_SEQ + schunk * 8;
        sAV0 = *(const f16x8*)(vg);
        sAV1 = *(const f16x8*)(vg + 8 * T_SEQ);
    }

    // ---- Q load + RoPE into B-frags qa[ds] (hides T0 latency) ----
    f16x8 qa[4];
    {
        const float* qrow = q + ((size_t)b * T_SEQ + tq) * 1024 + h * 64;
        float raw[4][8];
        #pragma unroll
        for (int ds = 0; ds < 4; ++ds) {
            f32x4 r0 = *(const f32x4*)(qrow + 16 * ds + 8 * hi);
            f32x4 r1 = *(const f32x4*)(qrow + 16 * ds + 8 * hi + 4);
            #pragma unroll
            for (int j = 0; j < 4; ++j) { raw[ds][j] = r0[j]; raw[ds][4 + j] = r1[j]; }
        }
        #pragma unroll
        for (int ds = 0; ds < 2; ++ds) {
            const float2* tp = tb + (size_t)tq * 32 + 16 * ds + 8 * hi;
            #pragma unroll
            for (int j = 0; j < 8; ++j) {
                float2 cs = tp[j];
                float x0 = raw[ds][j], x1 = raw[ds + 2][j];
                qa[ds][j]     = (_Float16)((x0 * cs.x - x1 * cs.y) * QSCALE);
                qa[ds + 2][j] = (_Float16)((x1 * cs.x + x0 * cs.y) * QSCALE);
            }
        }
    }

    // write T0 -> buf0, then issue T1 into setB
    *(f16x8*)(&smem[kd0])        = sAK0;
    *(f16x8*)(&smem[kd1])        = sAK1;
    *(f16x8*)(&smem[8192 + kd0]) = sAV0;
    *(f16x8*)(&smem[8192 + kd1]) = sAV1;
    {
        const _Float16* kg = kgbase + (size_t)(64 + srow) * 64 + schunk * 8;
        sBK0 = *(const f16x8*)(kg);
        sBK1 = *(const f16x8*)(kg + 8 * 64);
        const _Float16* vg = vgbase + (size_t)srow * T_SEQ + 64 + schunk * 8;
        sBV0 = *(const f16x8*)(vg);
        sBV1 = *(const f16x8*)(vg + 8 * T_SEQ);
    }
    __syncthreads();

    f32x16 o0, o1;                                 // O[q=crow(r,hi)][d = db*32+qc]
    #pragma unroll
    for (int i = 0; i < 16; ++i) { o0[i] = 0.f; o1[i] = 0.f; }
    float mrun = -INFINITY, lsum = 0.0f;

    // tile body: issue T(t+2) into set I, compute buf[t&1], write set O (T(t+1))
    auto tile_body = [&](int kvb,
                         f16x8& iK0, f16x8& iK1, f16x8& iV0, f16x8& iV1,
                         f16x8& oK0, f16x8& oK1, f16x8& oV0, f16x8& oV1) {
        if (kvb + 2 < NT) {
            const int nb = (kvb + 2) * 64;
            const _Float16* kg = kgbase + (size_t)(nb + srow) * 64 + schunk * 8;
            iK0 = *(const f16x8*)(kg);
            iK1 = *(const f16x8*)(kg + 8 * 64);
            const _Float16* vg = vgbase + (size_t)srow * T_SEQ + nb + schunk * 8;
            iV0 = *(const f16x8*)(vg);
            iV1 = *(const f16x8*)(vg + 8 * T_SEQ);
        }
        const _Float16* ks = smem + (kvb & 1) * 4096;
        const _Float16* vs = smem + 8192 + (kvb & 1) * 4096;

        const int rel = kvb * 64 - qlo;
        if (rel <= 0) {
            const bool act1 = (rel <= -32);
            // ---- QK^T: S^T[key 32][q 32] ----
            f32x16 s0, s1;
            #pragma unroll
            for (int i = 0; i < 16; ++i) { s0[i] = 0.f; s1[i] = 0.f; }
            __builtin_amdgcn_s_setprio(1);
            {
                const int krow = qc;
                const int rsw = krow & 7;
                #pragma unroll
                for (int ds = 0; ds < 4; ++ds) {
                    f16x8 ka = *(const f16x8*)(ks + krow * 64 + (((2*ds + hi) ^ rsw) * 8));
                    s0 = __builtin_amdgcn_mfma_f32_32x32x16_f16(ka, qa[ds], s0, 0, 0, 0);
                }
            }
            if (act1) {
                const int krow = 32 + qc;
                const int rsw = krow & 7;
                #pragma unroll
                for (int ds = 0; ds < 4; ++ds) {
                    f16x8 ka = *(const f16x8*)(ks + krow * 64 + (((2*ds + hi) ^ rsw) * 8));
                    s1 = __builtin_amdgcn_mfma_f32_32x32x16_f16(ka, qa[ds], s1, 0, 0, 0);
                }
            }
            __builtin_amdgcn_s_setprio(0);

            // ---- diagonal masking ----
            if (rel == 0) {
                #pragma unroll
                for (int r = 0; r < 16; ++r)
                    if ((r & 3) + 8 * (r >> 2) + 4 * hi > qc) s0[r] = -1e30f;
            }
            if (act1 && rel == -32) {
                #pragma unroll
                for (int r = 0; r < 16; ++r)
                    if ((r & 3) + 8 * (r >> 2) + 4 * hi > qc) s1[r] = -1e30f;
            }

            // ---- online softmax (log2 domain, defer-rescale THR=8) ----
            float pmL = s0[0];
            #pragma unroll
            for (int r = 1; r < 16; ++r) pmL = fmaxf(pmL, s0[r]);
            if (act1) {
                #pragma unroll
                for (int r = 0; r < 16; ++r) pmL = fmaxf(pmL, s1[r]);
            }
            if (!__all(pmL <= mrun + 8.0f)) {
                float pm = fmaxf(pmL, __shfl_xor(pmL, 32));
                float mn = fmaxf(mrun, pm);
                float corr = EXP2F(mrun - mn);
                mrun = mn;
                lsum *= corr;
                #pragma unroll
                for (int r = 0; r < 16; ++r) {
                    float cfr = __shfl(corr, (r & 3) + 8 * (r >> 2) + 4 * hi);
                    o0[r] *= cfr; o1[r] *= cfr;
                }
            }

            // ---- exp2 + pack P; accumulate row-sum ----
            unsigned pk0[8], pk1[8];
            float ps = 0.0f;
            #pragma unroll
            for (int i = 0; i < 8; ++i) {
                float p0 = EXP2F(s0[2*i]     - mrun);
                float p1 = EXP2F(s0[2*i + 1] - mrun);
                ps += p0 + p1;
                union { fp16x2b hh; unsigned u; } cv;
                cv.hh = __builtin_amdgcn_cvt_pkrtz(p0, p1);
                pk0[i] = cv.u;
            }
            if (act1) {
                #pragma unroll
                for (int i = 0; i < 8; ++i) {
                    float p0 = EXP2F(s1[2*i]     - mrun);
                    float p1 = EXP2F(s1[2*i + 1] - mrun);
                    ps += p0 + p1;
                    union { fp16x2b hh; unsigned u; } cv;
                    cv.hh = __builtin_amdgcn_cvt_pkrtz(p0, p1);
                    pk1[i] = cv.u;
                }
            }
            lsum += ps;

            // ---- P repack to PV A-frags ----
            union { unsigned u[4]; f16x8 v; } af[4];
            {
                unsigned t0 = (unsigned)__shfl_xor((int)(hi ? pk0[0] : pk0[2]), 32);
                unsigned t1 = (unsigned)__shfl_xor((int)(hi ? pk0[1] : pk0[3]), 32);
                unsigned t2 = (unsigned)__shfl_xor((int)(hi ? pk0[4] : pk0[6]), 32);
                unsigned t3 = (unsigned)__shfl_xor((int)(hi ? pk0[5] : pk0[7]), 32);
                af[0].u[0] = hi ? t0 : pk0[0]; af[0].u[1] = hi ? t1 : pk0[1];
                af[0].u[2] = hi ? pk0[2] : t0; af[0].u[3] = hi ? pk0[3] : t1;
                af[1].u[0] = hi ? t2 : pk0[4]; af[1].u[1] = hi ? t3 : pk0[5];
                af[1].u[2] = hi ? pk0[6] : t2; af[1].u[3] = hi ? pk0[7] : t3;
            }
            if (act1) {
                unsigned t0 = (unsigned)__shfl_xor((int)(hi ? pk1[0] : pk1[2]), 32);
                unsigned t1 = (unsigned)__shfl_xor((int)(hi ? pk1[1] : pk1[3]), 32);
                unsigned t2 = (unsigned)__shfl_xor((int)(hi ? pk1[4] : pk1[6]), 32);
                unsigned t3 = (unsigned)__shfl_xor((int)(hi ? pk1[5] : pk1[7]), 32);
                af[2].u[0] = hi ? t0 : pk1[0]; af[2].u[1] = hi ? t1 : pk1[1];
                af[2].u[2] = hi ? pk1[2] : t0; af[2].u[3] = hi ? pk1[3] : t1;
                af[3].u[0] = hi ? t2 : pk1[4]; af[3].u[1] = hi ? t3 : pk1[5];
                af[3].u[2] = hi ? pk1[6] : t2; af[3].u[3] = hi ? pk1[7] : t3;
            }

            // ---- PV ----
            __builtin_amdgcn_s_setprio(1);
            const int nkc = act1 ? 4 : 2;
            #pragma unroll
            for (int kc = 0; kc < 4; ++kc) {
                if (kc < nkc) {
                    const int vr0 = qc;
                    const int vr1 = 32 + qc;
                    f16x8 vb0 = *(const f16x8*)(vs + vr0 * 64 + (((2*kc + hi) ^ (vr0 & 7)) * 8));
                    f16x8 vb1 = *(const f16x8*)(vs + vr1 * 64 + (((2*kc + hi) ^ (vr1 & 7)) * 8));
                    o0 = __builtin_amdgcn_mfma_f32_32x32x16_f16(af[kc].v, vb0, o0, 0, 0, 0);
                    o1 = __builtin_amdgcn_mfma_f32_32x32x16_f16(af[kc].v, vb1, o1, 0, 0, 0);
                }
            }
            __builtin_amdgcn_s_setprio(0);
        }

        // write T(kvb+1) (loaded a full tile ago -> complete, no vmcnt stall)
        if (kvb + 1 < NT) {
            _Float16* kw = smem + ((kvb + 1) & 1) * 4096;
            _Float16* vw = smem + 8192 + ((kvb + 1) & 1) * 4096;
            *(f16x8*)(&kw[kd0]) = oK0;
            *(f16x8*)(&kw[kd1]) = oK1;
            *(f16x8*)(&vw[kd0]) = oV0;
            *(f16x8*)(&vw[kd1]) = oV1;
        }
        __syncthreads();
    };

    for (int t = 0; t < NT; ) {
        tile_body(t, sAK0, sAK1, sAV0, sAV1, sBK0, sBK1, sBV0, sBV1); ++t;
        if (t >= NT) break;
        tile_body(t, sBK0, sBK1, sBV0, sBV1, sAK0, sAK1, sAV0, sAV1); ++t;
    }

    // ---- epilogue: normalize (lane-pair merged lsum), LDS bounce, store ----
    lsum += __shfl_xor(lsum, 32);
    const float li = 1.0f / lsum;
    {
        _Float16* Os = smem;                       // [128][72]
        #pragma unroll
        for (int r = 0; r < 16; ++r) {
            const int crow = (r & 3) + 8 * (r >> 2) + 4 * hi;
            float lir = __shfl(li, crow);
            Os[(wid * 32 + crow) * 72 + qc]      = (_Float16)(o0[r] * lir);
            Os[(wid * 32 + crow) * 72 + 32 + qc] = (_Float16)(o1[r] * lir);
        }
    }
    __syncthreads();
    {
        const int row = tid >> 1, part = tid & 1;
        const _Float16* src = smem + row * 72 + part * 32;
        _Float16* dst = AO + ((size_t)b * T_SEQ + c * 128 + row) * 1024 + h * 64 + part * 32;
        #pragma unroll
        for (int j = 0; j < 4; ++j)
            *(f16x8*)(dst + j * 8) = *(const f16x8*)(src + j * 8);
    }
}

// ---------------- projection GEMM: out[4096][1024] = AO * Wt^T ----------------
// 128x64 tile (512 blocks -> 2 blocks/CU), BK=32, double-buffered LDS,
// padded stride 40 f16 to break the 8-way b128 read conflict.

#define AST 40
__global__ __launch_bounds__(256) void gemm_kernel(const _Float16* __restrict__ A,
                                                   const _Float16* __restrict__ Bt,
                                                   float* __restrict__ C)
{
    __shared__ _Float16 As[2][128 * AST];
    __shared__ _Float16 Bs[2][64 * AST];
    const int tid  = threadIdx.x;
    const int by   = blockIdx.x & 31;             // m-tile 0..31
    const int bx   = blockIdx.x >> 5;             // n-tile 0..15
    const int lane = tid & 63;
    const int wid  = tid >> 6;
    const int g = lane >> 4, r = lane & 15;
    const int wm = wid >> 1, wn = wid & 1;

    f32x4 acc[4][2];
    #pragma unroll
    for (int i = 0; i < 4; ++i)
        #pragma unroll
        for (int j = 0; j < 2; ++j) acc[i][j] = (f32x4){0.f,0.f,0.f,0.f};

    const int c0 = tid, c1 = tid + 256;           // A chunks (2/thread), B chunk (1)
    const size_t a0off = (size_t)(by*128 + (c0 >> 2)) * 1024 + (c0 & 3) * 8;
    const size_t a1off = (size_t)(by*128 + (c1 >> 2)) * 1024 + (c1 & 3) * 8;
    const size_t b0off = (size_t)(bx*64  + (c0 >> 2)) * 1024 + (c0 & 3) * 8;
    const int ad0 = (c0 >> 2) * AST + (c0 & 3) * 8;
    const int ad1 = (c1 >> 2) * AST + (c1 & 3) * 8;

    f16x8 a0 = *(const f16x8*)(A  + a0off);
    f16x8 a1 = *(const f16x8*)(A  + a1off);
    f16x8 b0 = *(const f16x8*)(Bt + b0off);
    *(f16x8*)(&As[0][ad0]) = a0;
    *(f16x8*)(&As[0][ad1]) = a1;
    *(f16x8*)(&Bs[0][ad0]) = b0;
    __syncthreads();
    int cur = 0;

    for (int kt = 0; kt < 32; ++kt) {
        if (kt < 31) {
            a0 = *(const f16x8*)(A  + a0off + (kt+1) * 32);
            a1 = *(const f16x8*)(A  + a1off + (kt+1) * 32);
            b0 = *(const f16x8*)(Bt + b0off + (kt+1) * 32);
        }
        f16x8 af[4], bfv[2];
        #pragma unroll
        for (int mi = 0; mi < 4; ++mi)
            af[mi] = *(const f16x8*)(&As[cur][(wm*64 + mi*16 + r) * AST + 8 * g]);
        #pragma unroll
        for (int ni = 0; ni < 2; ++ni)
            bfv[ni] = *(const f16x8*)(&Bs[cur][(wn*32 + ni*16 + r) * AST + 8 * g]);
        __builtin_amdgcn_s_setprio(1);
        #pragma unroll
        for (int mi = 0; mi < 4; ++mi)
            #pragma unroll
            for (int ni = 0; ni < 2; ++ni)
                acc[mi][ni] = __builtin_amdgcn_mfma_f32_16x16x32_f16(
                                  af[mi], bfv[ni], acc[mi][ni], 0, 0, 0);
        __builtin_amdgcn_s_setprio(0);
        if (kt < 31) {
            *(f16x8*)(&As[cur ^ 1][ad0]) = a0;
            *(f16x8*)(&As[cur ^ 1][ad1]) = a1;
            *(f16x8*)(&Bs[cur ^ 1][ad0]) = b0;
            cur ^= 1;
        }
        __syncthreads();
    }
    #pragma unroll
    for (int mi = 0; mi < 4; ++mi)
        #pragma unroll
        for (int ni = 0; ni < 2; ++ni)
            #pragma unroll
            for (int j = 0; j < 4; ++j)
                C[(size_t)(by*128 + wm*64 + mi*16 + 4*g + j) * 1024
                  + bx*64 + wn*32 + ni*16 + r] = acc[mi][ni][j];
}

// ---------------- launch ----------------

extern "C" void kernel_launch(void* const* d_in, const int* in_sizes, int n_in,
                              void* d_out, int out_size, void* d_ws, size_t ws_size,
                              hipStream_t stream) {
    const float* q = (const float*)d_in[0];
    const float* k = (const float*)d_in[1];
    const float* v = (const float*)d_in[2];
    const float* w = (const float*)d_in[3];
    float* out = (float*)d_out;

    char* ws = (char*)d_ws;                       // needs 15 MiB
    float2*   tb = (float2*)(ws);
    _Float16* Kr = (_Float16*)(ws + ((size_t)1 << 20));
    _Float16* Vt = (_Float16*)(ws + ((size_t)3 << 20));
    _Float16* Wt = (_Float16*)(ws + ((size_t)5 << 20));
    _Float16* AO = (_Float16*)(ws + ((size_t)7 << 20));

    hipLaunchKernelGGL(prep_kernel,  dim3(2816), dim3(256), 0, stream, k, v, w, tb, Kr, Vt, Wt);
    hipLaunchKernelGGL(attn_kernel,  dim3(512),  dim3(256), 0, stream, q, tb, Kr, Vt, AO);
    hipLaunchKernelGGL(gemm_kernel,  dim3(512),  dim3(256), 0, stream, AO, Wt, out);
}

// Round 8
// 79.980 us; speedup vs baseline: 1.1426x; 1.1426x over previous
//
#include <hip/hip_runtime.h>
#include <math.h>

#define T_SEQ 2048
#define NH    16
#define NKV   4
// ws layout: tb (sin/cos table, 512KB) @0 ; Kr f16 @1MB (2MB) ; Vt f16 @3MB (2MB) ;
//            Wt f16 @5MB (2MB) ; AO f16 @7MB (8MB). Total 15MB.

typedef __attribute__((ext_vector_type(8)))  _Float16 f16x8;
typedef __attribute__((ext_vector_type(4)))  _Float16 f16x4;
typedef __attribute__((ext_vector_type(2)))  __fp16   fp16x2b;  // cvt_pkrtz result type
typedef __attribute__((ext_vector_type(4)))  float    f32x4;
typedef __attribute__((ext_vector_type(16))) float    f32x16;

#if __has_builtin(__builtin_amdgcn_exp2f)
#define EXP2F(x) __builtin_amdgcn_exp2f(x)
#else
#define EXP2F(x) exp2f(x)
#endif

// 0.125 (1/sqrt(64)) * log2(e): QK^T scores land directly in log2 domain.
#define QSCALE 0.18033688011112042f

// LDS-producer barrier that does NOT drain vmcnt: global prefetch loads stay
// in flight across tiles (T4). lgkmcnt(0) makes this wave's ds_writes/reads
// visible/complete; sched_barrier(0) pins ordering (rule #18).
#define LDS_BARRIER()                                        \
    do {                                                     \
        __builtin_amdgcn_sched_barrier(0);                   \
        asm volatile("s_waitcnt lgkmcnt(0)" ::: "memory");   \
        __builtin_amdgcn_s_barrier();                        \
        __builtin_amdgcn_sched_barrier(0);                   \
    } while (0)

// ---------------- fused prep: table | rope_k | V-transpose | W-transpose ------
__global__ __launch_bounds__(256) void prep_kernel(const float* __restrict__ k,
                                                   const float* __restrict__ v,
                                                   const float* __restrict__ w,
                                                   float2* __restrict__ tb,
                                                   _Float16* __restrict__ Kr,
                                                   _Float16* __restrict__ Vt,
                                                   _Float16* __restrict__ Wt)
{
    __shared__ _Float16 L[64 * 72];
    const int bx = blockIdx.x;
    if (bx < 256) {
        // sin/cos table: tb[t*32+i] = {cos, sin}(t * 10000^(-i/32))
        int idx = bx * 256 + threadIdx.x;
        int i = idx & 31, t = idx >> 5;
        float inv = __expf((float)i * (-9.210340371976184f / 32.0f));
        float ang = (float)t * inv;
        tb[idx] = make_float2(cosf(ang), sinf(ang));
    } else if (bx < 2304) {
        // K RoPE (inline trig; independent of tb)
        int idx = (bx - 256) * 256 + threadIdx.x;     // [0, 2*4*2048*32)
        int i   = idx & 31;
        int t   = (idx >> 5) & 2047;
        int bk  = idx >> 16;                          // b*4+kh
        float inv = __expf((float)i * (-9.210340371976184f / 32.0f));
        float ang = (float)t * inv;
        float sn = sinf(ang), cs = cosf(ang);
        const float* src = k + ((size_t)(bk >> 2) * T_SEQ + t) * 256 + (bk & 3) * 64 + i;
        float x1 = src[0], x2 = src[32];
        _Float16* dst = Kr + ((size_t)bk * T_SEQ + t) * 64 + i;
        dst[0]  = (_Float16)(x1 * cs - x2 * sn);
        dst[32] = (_Float16)(x2 * cs + x1 * sn);
    } else if (bx < 2560) {
        // V transpose via LDS (both sides coalesced)
        const int id = bx - 2304;                     // 32 t-tiles x 8 bk
        const int t0 = (id & 31) * 64, bk = id >> 5;
        const int b = bk >> 2, kh = bk & 3;
        const int rr = threadIdx.x >> 2, pp = threadIdx.x & 3;
        const float* src = v + ((size_t)(b * T_SEQ + t0 + rr)) * 256 + kh * 64 + pp * 16;
        f32x4 s0 = *(const f32x4*)(src), s1 = *(const f32x4*)(src + 4);
        f32x4 s2 = *(const f32x4*)(src + 8), s3 = *(const f32x4*)(src + 12);
        _Float16* lp = &L[rr * 72 + pp * 16];
        #pragma unroll
        for (int j = 0; j < 4; ++j) { lp[j] = (_Float16)s0[j]; lp[4+j] = (_Float16)s1[j];
                                      lp[8+j] = (_Float16)s2[j]; lp[12+j] = (_Float16)s3[j]; }
        __syncthreads();
        f16x8 w0, w1;
        #pragma unroll
        for (int j = 0; j < 8; ++j) w0[j] = L[(pp * 16 + j) * 72 + rr];
        #pragma unroll
        for (int j = 0; j < 8; ++j) w1[j] = L[(pp * 16 + 8 + j) * 72 + rr];
        _Float16* dst = Vt + ((size_t)bk * 64 + rr) * T_SEQ + t0 + pp * 16;
        *(f16x8*)dst = w0; *(f16x8*)(dst + 8) = w1;
    } else {
        // W transpose via LDS
        const int id = bx - 2560;                     // 16 k-tiles x 16 n-tiles
        const int k0 = (id & 15) * 64, n0 = (id >> 4) * 64;
        const int rr = threadIdx.x >> 2, pp = threadIdx.x & 3;
        const float* src = w + (size_t)(k0 + rr) * 1024 + n0 + pp * 16;
        f32x4 s0 = *(const f32x4*)(src), s1 = *(const f32x4*)(src + 4);
        f32x4 s2 = *(const f32x4*)(src + 8), s3 = *(const f32x4*)(src + 12);
        _Float16* lp = &L[rr * 72 + pp * 16];
        #pragma unroll
        for (int j = 0; j < 4; ++j) { lp[j] = (_Float16)s0[j]; lp[4+j] = (_Float16)s1[j];
                                      lp[8+j] = (_Float16)s2[j]; lp[12+j] = (_Float16)s3[j]; }
        __syncthreads();
        f16x8 w0, w1;
        #pragma unroll
        for (int j = 0; j < 8; ++j) w0[j] = L[(pp * 16 + j) * 72 + rr];
        #pragma unroll
        for (int j = 0; j < 8; ++j) w1[j] = L[(pp * 16 + 8 + j) * 72 + rr];
        _Float16* dst = Wt + (size_t)(n0 + rr) * 1024 + k0 + pp * 16;
        *(f16x8*)dst = w0; *(f16x8*)(dst + 8) = w1;
    }
}

// ---------------- flash attention: 4 waves x 32q bands, 32x32 MFMA ----------
// COMPLEMENTARY pairing: all 512 blocks are co-resident (2/CU, no refill), so
// per-CU TOTAL work must be equal. CU gets bids (i, i+256) with chunk lengths
// NT(c) + NT(15-c) = 34 tile-units -- exactly equal on every CU.
// Raw-barrier pipeline: per-tile barrier drains lgkmcnt only; depth-2 global
// prefetch stays in flight across barriers (no vmcnt(0) in the loop).

__global__ __launch_bounds__(256) void attn_kernel(const float* __restrict__ q,
                                                   const float2* __restrict__ tb,
                                                   const _Float16* __restrict__ Kr,
                                                   const _Float16* __restrict__ Vt,
                                                   _Float16* __restrict__ AO)
{
    __shared__ _Float16 smem[16384];   // Ks[2]@0/4096, Vs[2]@8192/12288; Os reuse

    const int tid  = threadIdx.x;
    const int wid  = tid >> 6;
    const int lane = tid & 63;
    // ---- complementary task mapping: bid<256 -> c=15..8, bid>=256 -> c=0..7 ----
    const int bid = blockIdx.x;
    const int c   = (bid < 256) ? (15 - (bid >> 5)) : ((bid - 256) >> 5);
    const int bh  = bid & 31;                      // b*16+h (same for both halves)
    const int b = bh >> 4, h = bh & 15;
    const int bkh = b * NKV + (h >> 2);
    const int hi = lane >> 5;                      // half-wave
    const int qc = lane & 31;                      // q within band / A-row index
    const int qlo = c * 128 + wid * 32;            // wave's q band start
    const int tq  = qlo + qc;                      // this lane's stat-q row
    const int NT  = 2 * c + 2;

    // ---- staging geometry (256 threads stage 64x64 K + 64x64 V per tile) ----
    const int srow   = wid * 16 + (lane >> 3);
    const int schunk = lane & 7;
    const _Float16* kgbase = Kr + (size_t)bkh * T_SEQ * 64;
    const _Float16* vgbase = Vt + (size_t)bkh * 64 * T_SEQ;
    const int kd0 = srow * 64 + ((schunk ^ (srow & 7)) * 8);
    const int kd1 = kd0 + 8 * 64;

    // two named staging register sets (ping-pong; rule #20: no dynamic index)
    f16x8 sAK0, sAK1, sAV0, sAV1, sBK0, sBK1, sBV0, sBV1;
    {   // prologue: issue T0 loads first
        const _Float16* kg = kgbase + (size_t)srow * 64 + schunk * 8;
        sAK0 = *(const f16x8*)(kg);
        sAK1 = *(const f16x8*)(kg + 8 * 64);
        const _Float16* vg = vgbase + (size_t)srow * T_SEQ + schunk * 8;
        sAV0 = *(const f16x8*)(vg);
        sAV1 = *(const f16x8*)(vg + 8 * T_SEQ);
    }

    // ---- Q load + RoPE into B-frags qa[ds] (hides T0 latency) ----
    f16x8 qa[4];
    {
        const float* qrow = q + ((size_t)b * T_SEQ + tq) * 1024 + h * 64;
        float raw[4][8];
        #pragma unroll
        for (int ds = 0; ds < 4; ++ds) {
            f32x4 r0 = *(const f32x4*)(qrow + 16 * ds + 8 * hi);
            f32x4 r1 = *(const f32x4*)(qrow + 16 * ds + 8 * hi + 4);
            #pragma unroll
            for (int j = 0; j < 4; ++j) { raw[ds][j] = r0[j]; raw[ds][4 + j] = r1[j]; }
        }
        #pragma unroll
        for (int ds = 0; ds < 2; ++ds) {
            const float2* tp = tb + (size_t)tq * 32 + 16 * ds + 8 * hi;
            #pragma unroll
            for (int j = 0; j < 8; ++j) {
                float2 cs = tp[j];
                float x0 = raw[ds][j], x1 = raw[ds + 2][j];
                qa[ds][j]     = (_Float16)((x0 * cs.x - x1 * cs.y) * QSCALE);
                qa[ds + 2][j] = (_Float16)((x1 * cs.x + x0 * cs.y) * QSCALE);
            }
        }
    }

    // write T0 -> buf0, then issue T1 into setB
    *(f16x8*)(&smem[kd0])        = sAK0;
    *(f16x8*)(&smem[kd1])        = sAK1;
    *(f16x8*)(&smem[8192 + kd0]) = sAV0;
    *(f16x8*)(&smem[8192 + kd1]) = sAV1;
    {
        const _Float16* kg = kgbase + (size_t)(64 + srow) * 64 + schunk * 8;
        sBK0 = *(const f16x8*)(kg);
        sBK1 = *(const f16x8*)(kg + 8 * 64);
        const _Float16* vg = vgbase + (size_t)srow * T_SEQ + 64 + schunk * 8;
        sBV0 = *(const f16x8*)(vg);
        sBV1 = *(const f16x8*)(vg + 8 * T_SEQ);
    }
    LDS_BARRIER();

    f32x16 o0, o1;                                 // O[q=crow(r,hi)][d = db*32+qc]
    #pragma unroll
    for (int i = 0; i < 16; ++i) { o0[i] = 0.f; o1[i] = 0.f; }
    float mrun = -INFINITY, lsum = 0.0f;

    // tile body: issue T(t+2) into set I, compute buf[t&1], write set O (T(t+1))
    auto tile_body = [&](int kvb,
                         f16x8& iK0, f16x8& iK1, f16x8& iV0, f16x8& iV1,
                         f16x8& oK0, f16x8& oK1, f16x8& oV0, f16x8& oV1) {
        if (kvb + 2 < NT) {
            const int nb = (kvb + 2) * 64;
            const _Float16* kg = kgbase + (size_t)(nb + srow) * 64 + schunk * 8;
            iK0 = *(const f16x8*)(kg);
            iK1 = *(const f16x8*)(kg + 8 * 64);
            const _Float16* vg = vgbase + (size_t)srow * T_SEQ + nb + schunk * 8;
            iV0 = *(const f16x8*)(vg);
            iV1 = *(const f16x8*)(vg + 8 * T_SEQ);
        }
        const _Float16* ks = smem + (kvb & 1) * 4096;
        const _Float16* vs = smem + 8192 + (kvb & 1) * 4096;

        const int rel = kvb * 64 - qlo;
        if (rel <= 0) {
            const bool act1 = (rel <= -32);
            // ---- QK^T: S^T[key 32][q 32] ----
            f32x16 s0, s1;
            #pragma unroll
            for (int i = 0; i < 16; ++i) { s0[i] = 0.f; s1[i] = 0.f; }
            __builtin_amdgcn_s_setprio(1);
            {
                const int krow = qc;
                const int rsw = krow & 7;
                #pragma unroll
                for (int ds = 0; ds < 4; ++ds) {
                    f16x8 ka = *(const f16x8*)(ks + krow * 64 + (((2*ds + hi) ^ rsw) * 8));
                    s0 = __builtin_amdgcn_mfma_f32_32x32x16_f16(ka, qa[ds], s0, 0, 0, 0);
                }
            }
            if (act1) {
                const int krow = 32 + qc;
                const int rsw = krow & 7;
                #pragma unroll
                for (int ds = 0; ds < 4; ++ds) {
                    f16x8 ka = *(const f16x8*)(ks + krow * 64 + (((2*ds + hi) ^ rsw) * 8));
                    s1 = __builtin_amdgcn_mfma_f32_32x32x16_f16(ka, qa[ds], s1, 0, 0, 0);
                }
            }
            __builtin_amdgcn_s_setprio(0);

            // ---- diagonal masking ----
            if (rel == 0) {
                #pragma unroll
                for (int r = 0; r < 16; ++r)
                    if ((r & 3) + 8 * (r >> 2) + 4 * hi > qc) s0[r] = -1e30f;
            }
            if (act1 && rel == -32) {
                #pragma unroll
                for (int r = 0; r < 16; ++r)
                    if ((r & 3) + 8 * (r >> 2) + 4 * hi > qc) s1[r] = -1e30f;
            }

            // ---- online softmax (log2 domain, defer-rescale THR=8) ----
            float pmL = s0[0];
            #pragma unroll
            for (int r = 1; r < 16; ++r) pmL = fmaxf(pmL, s0[r]);
            if (act1) {
                #pragma unroll
                for (int r = 0; r < 16; ++r) pmL = fmaxf(pmL, s1[r]);
            }
            if (!__all(pmL <= mrun + 8.0f)) {
                float pm = fmaxf(pmL, __shfl_xor(pmL, 32));
                float mn = fmaxf(mrun, pm);
                float corr = EXP2F(mrun - mn);
                mrun = mn;
                lsum *= corr;
                #pragma unroll
                for (int r = 0; r < 16; ++r) {
                    float cfr = __shfl(corr, (r & 3) + 8 * (r >> 2) + 4 * hi);
                    o0[r] *= cfr; o1[r] *= cfr;
                }
            }

            // ---- exp2 + pack P; accumulate row-sum ----
            unsigned pk0[8], pk1[8];
            float ps = 0.0f;
            #pragma unroll
            for (int i = 0; i < 8; ++i) {
                float p0 = EXP2F(s0[2*i]     - mrun);
                float p1 = EXP2F(s0[2*i + 1] - mrun);
                ps += p0 + p1;
                union { fp16x2b hh; unsigned u; } cv;
                cv.hh = __builtin_amdgcn_cvt_pkrtz(p0, p1);
                pk0[i] = cv.u;
            }
            if (act1) {
                #pragma unroll
                for (int i = 0; i < 8; ++i) {
                    float p0 = EXP2F(s1[2*i]     - mrun);
                    float p1 = EXP2F(s1[2*i + 1] - mrun);
                    ps += p0 + p1;
                    union { fp16x2b hh; unsigned u; } cv;
                    cv.hh = __builtin_amdgcn_cvt_pkrtz(p0, p1);
                    pk1[i] = cv.u;
                }
            }
            lsum += ps;

            // ---- P repack to PV A-frags ----
            union { unsigned u[4]; f16x8 v; } af[4];
            {
                unsigned t0 = (unsigned)__shfl_xor((int)(hi ? pk0[0] : pk0[2]), 32);
                unsigned t1 = (unsigned)__shfl_xor((int)(hi ? pk0[1] : pk0[3]), 32);
                unsigned t2 = (unsigned)__shfl_xor((int)(hi ? pk0[4] : pk0[6]), 32);
                unsigned t3 = (unsigned)__shfl_xor((int)(hi ? pk0[5] : pk0[7]), 32);
                af[0].u[0] = hi ? t0 : pk0[0]; af[0].u[1] = hi ? t1 : pk0[1];
                af[0].u[2] = hi ? pk0[2] : t0; af[0].u[3] = hi ? pk0[3] : t1;
                af[1].u[0] = hi ? t2 : pk0[4]; af[1].u[1] = hi ? t3 : pk0[5];
                af[1].u[2] = hi ? pk0[6] : t2; af[1].u[3] = hi ? pk0[7] : t3;
            }
            if (act1) {
                unsigned t0 = (unsigned)__shfl_xor((int)(hi ? pk1[0] : pk1[2]), 32);
                unsigned t1 = (unsigned)__shfl_xor((int)(hi ? pk1[1] : pk1[3]), 32);
                unsigned t2 = (unsigned)__shfl_xor((int)(hi ? pk1[4] : pk1[6]), 32);
                unsigned t3 = (unsigned)__shfl_xor((int)(hi ? pk1[5] : pk1[7]), 32);
                af[2].u[0] = hi ? t0 : pk1[0]; af[2].u[1] = hi ? t1 : pk1[1];
                af[2].u[2] = hi ? pk1[2] : t0; af[2].u[3] = hi ? pk1[3] : t1;
                af[3].u[0] = hi ? t2 : pk1[4]; af[3].u[1] = hi ? t3 : pk1[5];
                af[3].u[2] = hi ? pk1[6] : t2; af[3].u[3] = hi ? pk1[7] : t3;
            }

            // ---- PV ----
            __builtin_amdgcn_s_setprio(1);
            const int nkc = act1 ? 4 : 2;
            #pragma unroll
            for (int kc = 0; kc < 4; ++kc) {
                if (kc < nkc) {
                    const int vr0 = qc;
                    const int vr1 = 32 + qc;
                    f16x8 vb0 = *(const f16x8*)(vs + vr0 * 64 + (((2*kc + hi) ^ (vr0 & 7)) * 8));
                    f16x8 vb1 = *(const f16x8*)(vs + vr1 * 64 + (((2*kc + hi) ^ (vr1 & 7)) * 8));
                    o0 = __builtin_amdgcn_mfma_f32_32x32x16_f16(af[kc].v, vb0, o0, 0, 0, 0);
                    o1 = __builtin_amdgcn_mfma_f32_32x32x16_f16(af[kc].v, vb1, o1, 0, 0, 0);
                }
            }
            __builtin_amdgcn_s_setprio(0);
        }

        // write T(kvb+1) (loaded a full tile ago -> complete, no vmcnt stall)
        if (kvb + 1 < NT) {
            _Float16* kw = smem + ((kvb + 1) & 1) * 4096;
            _Float16* vw = smem + 8192 + ((kvb + 1) & 1) * 4096;
            *(f16x8*)(&kw[kd0]) = oK0;
            *(f16x8*)(&kw[kd1]) = oK1;
            *(f16x8*)(&vw[kd0]) = oV0;
            *(f16x8*)(&vw[kd1]) = oV1;
        }
        LDS_BARRIER();   // drains LDS only; global prefetch stays in flight
    };

    for (int t = 0; t < NT; ) {
        tile_body(t, sAK0, sAK1, sAV0, sAV1, sBK0, sBK1, sBV0, sBV1); ++t;
        if (t >= NT) break;
        tile_body(t, sBK0, sBK1, sBV0, sBV1, sAK0, sAK1, sAV0, sAV1); ++t;
    }

    // ---- epilogue: normalize (lane-pair merged lsum), LDS bounce, store ----
    lsum += __shfl_xor(lsum, 32);
    const float li = 1.0f / lsum;
    __syncthreads();   // full drain before reusing smem as Os
    {
        _Float16* Os = smem;                       // [128][72]
        #pragma unroll
        for (int r = 0; r < 16; ++r) {
            const int crow = (r & 3) + 8 * (r >> 2) + 4 * hi;
            float lir = __shfl(li, crow);
            Os[(wid * 32 + crow) * 72 + qc]      = (_Float16)(o0[r] * lir);
            Os[(wid * 32 + crow) * 72 + 32 + qc] = (_Float16)(o1[r] * lir);
        }
    }
    __syncthreads();
    {
        const int row = tid >> 1, part = tid & 1;
        const _Float16* src = smem + row * 72 + part * 32;
        _Float16* dst = AO + ((size_t)b * T_SEQ + c * 128 + row) * 1024 + h * 64 + part * 32;
        #pragma unroll
        for (int j = 0; j < 4; ++j)
            *(f16x8*)(dst + j * 8) = *(const f16x8*)(src + j * 8);
    }
}

// ---------------- projection GEMM: out[4096][1024] = AO * Wt^T ----------------
// 128x64 tile (512 blocks -> 2 blocks/CU), BK=32, double-buffered LDS,
// padded stride 40 f16 to break the 8-way b128 read conflict.

#define AST 40
__global__ __launch_bounds__(256) void gemm_kernel(const _Float16* __restrict__ A,
                                                   const _Float16* __restrict__ Bt,
                                                   float* __restrict__ C)
{
    __shared__ _Float16 As[2][128 * AST];
    __shared__ _Float16 Bs[2][64 * AST];
    const int tid  = threadIdx.x;
    const int by   = blockIdx.x & 31;             // m-tile 0..31
    const int bx   = blockIdx.x >> 5;             // n-tile 0..15
    const int lane = tid & 63;
    const int wid  = tid >> 6;
    const int g = lane >> 4, r = lane & 15;
    const int wm = wid >> 1, wn = wid & 1;

    f32x4 acc[4][2];
    #pragma unroll
    for (int i = 0; i < 4; ++i)
        #pragma unroll
        for (int j = 0; j < 2; ++j) acc[i][j] = (f32x4){0.f,0.f,0.f,0.f};

    const int c0 = tid, c1 = tid + 256;           // A chunks (2/thread), B chunk (1)
    const size_t a0off = (size_t)(by*128 + (c0 >> 2)) * 1024 + (c0 & 3) * 8;
    const size_t a1off = (size_t)(by*128 + (c1 >> 2)) * 1024 + (c1 & 3) * 8;
    const size_t b0off = (size_t)(bx*64  + (c0 >> 2)) * 1024 + (c0 & 3) * 8;
    const int ad0 = (c0 >> 2) * AST + (c0 & 3) * 8;
    const int ad1 = (c1 >> 2) * AST + (c1 & 3) * 8;

    f16x8 a0 = *(const f16x8*)(A  + a0off);
    f16x8 a1 = *(const f16x8*)(A  + a1off);
    f16x8 b0 = *(const f16x8*)(Bt + b0off);
    *(f16x8*)(&As[0][ad0]) = a0;
    *(f16x8*)(&As[0][ad1]) = a1;
    *(f16x8*)(&Bs[0][ad0]) = b0;
    __syncthreads();
    int cur = 0;

    for (int kt = 0; kt < 32; ++kt) {
        if (kt < 31) {
            a0 = *(const f16x8*)(A  + a0off + (kt+1) * 32);
            a1 = *(const f16x8*)(A  + a1off + (kt+1) * 32);
            b0 = *(const f16x8*)(Bt + b0off + (kt+1) * 32);
        }
        f16x8 af[4], bfv[2];
        #pragma unroll
        for (int mi = 0; mi < 4; ++mi)
            af[mi] = *(const f16x8*)(&As[cur][(wm*64 + mi*16 + r) * AST + 8 * g]);
        #pragma unroll
        for (int ni = 0; ni < 2; ++ni)
            bfv[ni] = *(const f16x8*)(&Bs[cur][(wn*32 + ni*16 + r) * AST + 8 * g]);
        __builtin_amdgcn_s_setprio(1);
        #pragma unroll
        for (int mi = 0; mi < 4; ++mi)
            #pragma unroll
            for (int ni = 0; ni < 2; ++ni)
                acc[mi][ni] = __builtin_amdgcn_mfma_f32_16x16x32_f16(
                                  af[mi], bfv[ni], acc[mi][ni], 0, 0, 0);
        __builtin_amdgcn_s_setprio(0);
        if (kt < 31) {
            *(f16x8*)(&As[cur ^ 1][ad0]) = a0;
            *(f16x8*)(&As[cur ^ 1][ad1]) = a1;
            *(f16x8*)(&Bs[cur ^ 1][ad0]) = b0;
            cur ^= 1;
        }
        __syncthreads();
    }
    #pragma unroll
    for (int mi = 0; mi < 4; ++mi)
        #pragma unroll
        for (int ni = 0; ni < 2; ++ni)
            #pragma unroll
            for (int j = 0; j < 4; ++j)
                C[(size_t)(by*128 + wm*64 + mi*16 + 4*g + j) * 1024
                  + bx*64 + wn*32 + ni*16 + r] = acc[mi][ni][j];
}

// ---------------- launch ----------------

extern "C" void kernel_launch(void* const* d_in, const int* in_sizes, int n_in,
                              void* d_out, int out_size, void* d_ws, size_t ws_size,
                              hipStream_t stream) {
    const float* q = (const float*)d_in[0];
    const float* k = (const float*)d_in[1];
    const float* v = (const float*)d_in[2];
    const float* w = (const float*)d_in[3];
    float* out = (float*)d_out;

    char* ws = (char*)d_ws;                       // needs 15 MiB
    float2*   tb = (float2*)(ws);
    _Float16* Kr = (_Float16*)(ws + ((size_t)1 << 20));
    _Float16* Vt = (_Float16*)(ws + ((size_t)3 << 20));
    _Float16* Wt = (_Float16*)(ws + ((size_t)5 << 20));
    _Float16* AO = (_Float16*)(ws + ((size_t)7 << 20));

    hipLaunchKernelGGL(prep_kernel,  dim3(2816), dim3(256), 0, stream, k, v, w, tb, Kr, Vt, Wt);
    hipLaunchKernelGGL(attn_kernel,  dim3(512),  dim3(256), 0, stream, q, tb, Kr, Vt, AO);
    hipLaunchKernelGGL(gemm_kernel,  dim3(512),  dim3(256), 0, stream, AO, Wt, out);
}